// Round 1
// baseline (15.350 us; speedup 1.0000x reference)
//
#include <hip/hip_runtime.h>

// SoftSort: P[b,i,j] = softmax_j((s_j - s_i)/tau) = softmax_j(s_j/tau)  (i-independent!)
// => out[b,i,c] = (sum_j exp(s_j) F[b,j,c]) / (sum_j exp(s_j))  for every i.
// Pass 1: per-(batch, j-slice) partial weighted sums. Pass 2: reduce + broadcast.

static constexpr int B = 4;
static constexpr int N = 4096;
static constexpr int C = 64;
static constexpr int S = 16;                 // j-slices per batch in pass 1
static constexpr int PART_STRIDE = C + 1;    // 64 channel sums + 1 denom
static constexpr int RPB = 64;               // output rows per block in pass 2

__global__ __launch_bounds__(256) void softsort_partial(
    const float* __restrict__ scores,        // (B,N)
    const float* __restrict__ feat,          // (B,N,C)
    float* __restrict__ part) {              // (B,S,C+1)
  const int b = blockIdx.x / S;
  const int s = blockIdx.x % S;
  const int tid = (int)threadIdx.x;          // 256 threads
  const int c = tid & (C - 1);               // channel 0..63
  const int r = tid >> 6;                    // 0..3 parallel j-rows
  const int jpb = N / S;                     // 256 j's per slice
  const int j0 = s * jpb;

  const float* sb = scores + (size_t)b * N;
  const float* fb = feat + (size_t)b * N * C;

  float acc = 0.0f;                          // sum_j w_j * F[j,c] over this slice
  float dacc = 0.0f;                         // sum_j w_j (redundant across c, used by c==0)
  for (int j = j0 + r; j < j0 + jpb; j += 4) {
    const float w = __expf(sb[j]);           // TAU == 1.0
    acc += w * fb[(size_t)j * C + c];
    dacc += w;
  }

  __shared__ float lds[4][PART_STRIDE];
  lds[r][c] = acc;
  if (c == 0) lds[r][C] = dacc;
  __syncthreads();

  if (tid < PART_STRIDE) {
    const float sum = lds[0][tid] + lds[1][tid] + lds[2][tid] + lds[3][tid];
    part[(size_t)(b * S + s) * PART_STRIDE + tid] = sum;
  }
}

__global__ __launch_bounds__(256) void softsort_finalize(
    const float* __restrict__ part,          // (B,S,C+1)
    float* __restrict__ out) {               // (B,N,C)
  const int blocksPerBatch = N / RPB;        // 64
  const int b = blockIdx.x / blocksPerBatch;
  const int rb = blockIdx.x % blocksPerBatch;
  const int tid = (int)threadIdx.x;          // 256 threads

  __shared__ float rowv[C];                  // normalized row, shared by all output rows
  __shared__ float denom_s;

  if (tid < PART_STRIDE) {
    const float* p = part + (size_t)b * S * PART_STRIDE + tid;
    float sum = 0.0f;
#pragma unroll
    for (int s2 = 0; s2 < S; ++s2) sum += p[(size_t)s2 * PART_STRIDE];
    if (tid < C) rowv[tid] = sum;
    else        denom_s = sum;
  }
  __syncthreads();
  const float inv = 1.0f / denom_s;

  float4* dst = (float4*)(out + (size_t)b * N * C + (size_t)rb * RPB * C);
  const int nvec = RPB * C / 4;              // 1024 float4 per block
#pragma unroll
  for (int idx = tid; idx < nvec; idx += 256) {
    const int c4 = (idx & (C / 4 - 1)) * 4;  // channel group
    const float4 v = make_float4(rowv[c4 + 0] * inv, rowv[c4 + 1] * inv,
                                 rowv[c4 + 2] * inv, rowv[c4 + 3] * inv);
    dst[idx] = v;
  }
}

extern "C" void kernel_launch(void* const* d_in, const int* in_sizes, int n_in,
                              void* d_out, int out_size, void* d_ws, size_t ws_size,
                              hipStream_t stream) {
  const float* scores = (const float*)d_in[0];   // (B,N,1) fp32
  const float* feat   = (const float*)d_in[1];   // (B,N,C) fp32
  float* out  = (float*)d_out;                   // (B,N,C) fp32
  float* part = (float*)d_ws;                    // B*S*(C+1) floats = 16,640 B

  softsort_partial<<<B * S, 256, 0, stream>>>(scores, feat, part);
  softsort_finalize<<<B * (N / RPB), 256, 0, stream>>>(part, out);
}

// Round 2
// 12.877 us; speedup vs baseline: 1.1920x; 1.1920x over previous
//
#include <hip/hip_runtime.h>

// SoftSort: P[b,i,j] = softmax_j((s_j - s_i)/tau) = softmax_j(s_j/tau)  (i-independent)
// => out[b,i,c] = (sum_j exp(s_j) F[b,j,c]) / (sum_j exp(s_j))  for every i.
// Pass 1: per-(batch, 64-row slice) partial weighted sums, float4 feature loads.
// Pass 2: reduce 64 partials per batch (redundantly per block) + broadcast rows.

static constexpr int B = 4;
static constexpr int N = 4096;
static constexpr int C = 64;
static constexpr int S = 64;                 // j-slices per batch (pass 1 blocks/batch)
static constexpr int JPS = N / S;            // 64 rows per slice
static constexpr int PART_STRIDE = C + 1;    // 64 channel sums + 1 denom
static constexpr int RPB = 64;               // output rows per block in pass 2

__global__ __launch_bounds__(256) void softsort_partial(
    const float* __restrict__ scores,        // (B,N)
    const float* __restrict__ feat,          // (B,N,C)
    float* __restrict__ part) {              // (B,S,C+1)
  const int b   = blockIdx.x >> 6;           // /64
  const int sl  = blockIdx.x & 63;
  const int tid = (int)threadIdx.x;          // 256 threads
  const int j0  = sl * JPS;

  __shared__ float wsh[JPS];                 // exp(score) per row of this slice
  if (tid < JPS) wsh[tid] = __expf(scores[(size_t)b * N + j0 + tid]);
  __syncthreads();

  const int cg = tid & 15;                   // channel group: channels 4*cg..4*cg+3
  const int rl = tid >> 4;                   // row lane 0..15

  const float4* fb = (const float4*)(feat + ((size_t)b * N + j0) * C);

  float4 acc = make_float4(0.f, 0.f, 0.f, 0.f);
  float dacc = 0.f;                          // sum of w over this rl's 4 rows
#pragma unroll
  for (int it = 0; it < 4; ++it) {
    const int r = it * 16 + rl;              // row within slice
    const float w = wsh[r];
    const float4 f = fb[r * 16 + cg];        // 16 float4 per row
    acc.x += w * f.x; acc.y += w * f.y;
    acc.z += w * f.z; acc.w += w * f.w;
    dacc += w;
  }

  __shared__ float ldsA[16][C];              // [rl][channel]
  __shared__ float ldsD[16];                 // [rl] denom partial
  *(float4*)&ldsA[rl][4 * cg] = acc;
  if (cg == 0) ldsD[rl] = dacc;
  __syncthreads();

  if (tid < PART_STRIDE) {
    float sum = 0.f;
    if (tid < C) {
#pragma unroll
      for (int r = 0; r < 16; ++r) sum += ldsA[r][tid];
    } else {
#pragma unroll
      for (int r = 0; r < 16; ++r) sum += ldsD[r];
    }
    part[(size_t)(b * S + sl) * PART_STRIDE + tid] = sum;
  }
}

__global__ __launch_bounds__(256) void softsort_finalize(
    const float* __restrict__ part,          // (B,S,C+1)
    float* __restrict__ out) {               // (B,N,C)
  const int blocksPerBatch = N / RPB;        // 64
  const int b   = blockIdx.x / blocksPerBatch;
  const int rb  = blockIdx.x % blocksPerBatch;
  const int tid = (int)threadIdx.x;          // 256 threads

  __shared__ float rowv[C];
  __shared__ float denom_s;

  if (tid < PART_STRIDE) {
    const float* p = part + (size_t)b * S * PART_STRIDE + tid;
    float sum = 0.f;
#pragma unroll
    for (int s2 = 0; s2 < S; ++s2) sum += p[(size_t)s2 * PART_STRIDE];
    if (tid < C) rowv[tid] = sum;
    else         denom_s = sum;
  }
  __syncthreads();
  const float inv = 1.0f / denom_s;

  // Each thread's channel group is invariant across its 4 stores (256 % 16 == 0).
  const int c4 = (tid & (C / 4 - 1)) * 4;
  const float4 v = make_float4(rowv[c4 + 0] * inv, rowv[c4 + 1] * inv,
                               rowv[c4 + 2] * inv, rowv[c4 + 3] * inv);

  float4* dst = (float4*)(out + (size_t)b * N * C + (size_t)rb * RPB * C);
  const int nvec = RPB * C / 4;              // 1024 float4 per block
#pragma unroll
  for (int idx = tid; idx < nvec; idx += 256) {
    dst[idx] = v;
  }
}

extern "C" void kernel_launch(void* const* d_in, const int* in_sizes, int n_in,
                              void* d_out, int out_size, void* d_ws, size_t ws_size,
                              hipStream_t stream) {
  const float* scores = (const float*)d_in[0];   // (B,N,1) fp32
  const float* feat   = (const float*)d_in[1];   // (B,N,C) fp32
  float* out  = (float*)d_out;                   // (B,N,C) fp32
  float* part = (float*)d_ws;                    // B*S*(C+1) floats = 66,560 B

  softsort_partial<<<B * S, 256, 0, stream>>>(scores, feat, part);
  softsort_finalize<<<B * (N / RPB), 256, 0, stream>>>(part, out);
}